// Round 10
// baseline (164.467 us; speedup 1.0000x reference)
//
#include <hip/hip_runtime.h>
#include <hip/hip_cooperative_groups.h>

namespace cg = cooperative_groups;

#define N 512          // n = 2*B
#define B 256
#define D 512
#define NT 512
#define GRID 256

// ws float offsets
#define WS_SL    0                    // [N] sorted labels ascending
#define WS_NORM  512                  // [N] ||f16||^2 (fp32) by sorted position
#define WS_PART  1024                 // [GRID] per-block partials
#define WS_FH    2048                 // N*D _Float16 sorted features (512 KB)
#define WS_G     (2048 + (N * D) / 2) // [N*N] fp32 Gram, sorted order (1 MB)

typedef _Float16 half8_t __attribute__((ext_vector_type(8)));
typedef float    f32x4   __attribute__((ext_vector_type(4)));

__global__ __launch_bounds__(NT) void rnc_all(
    const float* __restrict__ wt, const float* __restrict__ mt,
    const float* __restrict__ lwt, const float* __restrict__ lmt,
    float* __restrict__ ws, float* __restrict__ out)
{
    cg::grid_group gridg = cg::this_grid();
    const int b = blockIdx.x, t = threadIdx.x;
    const int w = t >> 6, lane = t & 63;

    __shared__ float slab[N];          // labels (orig) -> sorted labels in ph3
    __shared__ float snm[N];
    __shared__ __align__(16) float sp0[N];
    __shared__ __align__(16) float sf0[N];
    __shared__ __align__(16) float sp1[N];
    __shared__ __align__(16) float sf1[N];
    __shared__ float srA[8], srB[8];
    __shared__ int   sri[8];
    __shared__ int   sr01;

    // ================= phase 1: rank + cvt/permute rows 2b, 2b+1 ==========
    const int j0 = 2 * b, j1 = 2 * b + 1;       // original rows owned
    slab[t] = (t < B) ? lwt[t] : lmt[t - B];
    __syncthreads();
    const float lj0 = slab[j0], lj1 = slab[j1];
    {
        const float v = slab[t];
        int c = ((v < lj0 || (v == lj0 && t < j0)) ? 1 : 0)
              + ((v < lj1 || (v == lj1 && t < j1)) ? 0x10000 : 0);
        #pragma unroll
        for (int off = 32; off > 0; off >>= 1) c += __shfl_down(c, off, 64);
        if (lane == 0) sri[w] = c;
    }
    __syncthreads();
    if (t == 0) {
        int s = 0;
        #pragma unroll
        for (int k = 0; k < 8; ++k) s += sri[k];
        sr01 = s;
    }
    __syncthreads();
    const int r0 = sr01 & 0xffff, r1 = sr01 >> 16;   // sorted slots

    {   // convert element t of both rows; norms of the rounded values
        const float* F0 = (j0 < B) ? (wt + (size_t)j0 * D) : (mt + (size_t)(j0 - B) * D);
        const float* F1 = (j1 < B) ? (wt + (size_t)j1 * D) : (mt + (size_t)(j1 - B) * D);
        const _Float16 h0 = (_Float16)F0[t];
        const _Float16 h1 = (_Float16)F1[t];
        _Float16* fh = (_Float16*)(ws + WS_FH);
        fh[(size_t)r0 * D + t] = h0;
        fh[(size_t)r1 * D + t] = h1;
        float n0 = (float)h0 * (float)h0;
        float n1 = (float)h1 * (float)h1;
        #pragma unroll
        for (int off = 32; off > 0; off >>= 1) {
            n0 += __shfl_down(n0, off, 64);
            n1 += __shfl_down(n1, off, 64);
        }
        if (lane == 0) { srA[w] = n0; srB[w] = n1; }
    }
    __syncthreads();
    if (t == 0) {
        float s0 = 0.f, s1 = 0.f;
        #pragma unroll
        for (int k = 0; k < 8; ++k) { s0 += srA[k]; s1 += srB[k]; }
        ws[WS_NORM + r0] = s0;
        ws[WS_NORM + r1] = s1;
        ws[WS_SL + r0] = lj0;
        ws[WS_SL + r1] = lj1;
    }
    gridg.sync();

    // ================= phase 2: MFMA Gram (sorted fp16) ====================
    {
        const int wid = b * 8 + w;               // 0..2047; tiles 0..1023
        if (wid < 1024) {
            const int ti = wid >> 5, tj = wid & 31;
            const int quad = lane >> 4, m = lane & 15;
            const _Float16* fh = (const _Float16*)(ws + WS_FH);
            const _Float16* Arow = fh + (size_t)(ti * 16 + m) * D + quad * 8;
            const _Float16* Brow = fh + (size_t)(tj * 16 + m) * D + quad * 8;
            f32x4 acc = {0.f, 0.f, 0.f, 0.f};
            #pragma unroll
            for (int k0 = 0; k0 < D; k0 += 32) {
                const half8_t a  = *(const half8_t*)(Arow + k0);
                const half8_t b2 = *(const half8_t*)(Brow + k0);
                acc = __builtin_amdgcn_mfma_f32_16x16x32_f16(a, b2, acc, 0, 0, 0);
            }
            float* G = ws + WS_G;
            const int col = tj * 16 + m;
            #pragma unroll
            for (int rg = 0; rg < 4; ++rg)
                G[(size_t)(ti * 16 + quad * 4 + rg) * N + col] = acc[rg];
        }
    }
    gridg.sync();

    // ================= phase 3: main (sorted rows i0, i1) ==================
    const int i0 = 2 * b, i1 = 2 * b + 1;        // sorted positions
    slab[t] = ws[WS_SL + t];                      // now sorted labels
    snm[t]  = ws[WS_NORM + t];
    __syncthreads();
    const float li0 = slab[i0], li1 = slab[i1];
    const float ni0 = snm[i0],  ni1 = snm[i1];

    {   // e from Gram rows (coalesced)
        const float* G = ws + WS_G;
        const float g0 = G[(size_t)i0 * N + t];
        const float g1 = G[(size_t)i1 * N + t];
        const float d0 = fmaxf(ni0 + snm[t] - 2.f * g0, 0.f);
        const float d1 = fmaxf(ni1 + snm[t] - 2.f * g1, 0.f);
        const float lg0 = -0.5f * sqrtf(d0);
        const float lg1 = -0.5f * sqrtf(d1);
        float lg_acc = 0.f;
        if (t != i0) lg_acc += lg0;
        if (t != i1) lg_acc += lg1;
        const float e0 = (t == i0) ? 0.f : __expf(lg0);
        const float e1 = (t == i1) ? 0.f : __expf(lg1);
        sp0[t] = e0; sf0[t] = e0;
        sp1[t] = e1; sf1[t] = e1;
        srA[0] = 0.f;                             // reuse for final reduce
        // stash lg_acc for after scans via registers
        __syncthreads();

        // wave-parallel scans
        if (w < 4) {
            float* arr = (w == 0) ? sp0 : (w == 1) ? sf0 : (w == 2) ? sp1 : sf1;
            float4* a4 = (float4*)arr;
            float4 u0 = a4[lane * 2], u1 = a4[lane * 2 + 1];
            float v0 = u0.x, v1 = u0.y, v2 = u0.z, v3 = u0.w;
            float v4 = u1.x, v5 = u1.y, v6 = u1.z, v7 = u1.w;
            if ((w & 1) == 0) {                   // inclusive prefix scan
                v1 += v0; v2 += v1; v3 += v2; v4 += v3; v5 += v4; v6 += v5; v7 += v6;
                float x = v7;
                #pragma unroll
                for (int off = 1; off < 64; off <<= 1) {
                    const float y = __shfl_up(x, off, 64);
                    if (lane >= off) x += y;
                }
                float ex = __shfl_up(x, 1, 64);
                if (lane == 0) ex = 0.f;
                v0 += ex; v1 += ex; v2 += ex; v3 += ex;
                v4 += ex; v5 += ex; v6 += ex; v7 += ex;
            } else {                              // inclusive suffix scan
                v6 += v7; v5 += v6; v4 += v5; v3 += v4; v2 += v3; v1 += v2; v0 += v1;
                float x = v0;
                #pragma unroll
                for (int off = 1; off < 64; off <<= 1) {
                    const float y = __shfl_down(x, off, 64);
                    if (lane + off < 64) x += y;
                }
                float ex = __shfl_down(x, 1, 64);
                if (lane == 63) ex = 0.f;
                v0 += ex; v1 += ex; v2 += ex; v3 += ex;
                v4 += ex; v5 += ex; v6 += ex; v7 += ex;
            }
            a4[lane * 2]     = make_float4(v0, v1, v2, v3);
            a4[lane * 2 + 1] = make_float4(v4, v5, v6, v7);
        }
        __syncthreads();

        // per-k denom via two exact binary searches (ri == i)
        float local = lg_acc;
        #pragma unroll
        for (int p = 0; p < 2; ++p) {
            const int x = t;
            const int ri = p ? i1 : i0;
            const float li = p ? li1 : li0;
            const float* SP = p ? sp1 : sp0;
            const float* SF = p ? sf1 : sf0;
            if (x != ri) {
                const float th = fabsf(li - slab[x]);
                int lo = 0, hi = ri + 1;          // left: weakly decreasing
                while (lo < hi) {
                    const int mid = (lo + hi) >> 1;
                    if (fabsf(li - slab[mid]) >= th) lo = mid + 1; else hi = mid;
                }
                const int a = lo;
                lo = ri + 1; hi = N;              // right: weakly increasing
                while (lo < hi) {
                    const int mid = (lo + hi) >> 1;
                    if (fabsf(li - slab[mid]) >= th) hi = mid; else lo = mid + 1;
                }
                const int bb2 = lo;
                const float denom = ((a > 0) ? SP[a - 1] : 0.f)
                                  + ((bb2 < N) ? SF[bb2] : 0.f);
                local -= __logf(denom);
            }
        }

        // block reduction -> partial
        #pragma unroll
        for (int off = 32; off > 0; off >>= 1)
            local += __shfl_down(local, off, 64);
        if (lane == 0) srA[w] = local;
        __syncthreads();
        if (t == 0) {
            float sum = 0.f;
            #pragma unroll
            for (int k = 0; k < 8; ++k) sum += srA[k];
            ws[WS_PART + b] = sum;
        }
    }
    gridg.sync();

    // ================= phase 4: block 0 reduces partials ===================
    if (b == 0) {
        float v2 = (t < GRID) ? ws[WS_PART + t] : 0.f;
        #pragma unroll
        for (int off = 32; off > 0; off >>= 1)
            v2 += __shfl_down(v2, off, 64);
        if (lane == 0) srB[w] = v2;
        __syncthreads();
        if (t == 0) {
            float sum = 0.f;
            #pragma unroll
            for (int k = 0; k < 8; ++k) sum += srB[k];
            out[0] = -sum / (float)((long)N * (N - 1));
        }
    }
}

extern "C" void kernel_launch(void* const* d_in, const int* in_sizes, int n_in,
                              void* d_out, int out_size, void* d_ws, size_t ws_size,
                              hipStream_t stream) {
    const float* wt  = (const float*)d_in[0];
    const float* mt  = (const float*)d_in[1];
    const float* lwt = (const float*)d_in[2];
    const float* lmt = (const float*)d_in[3];
    float* out = (float*)d_out;
    float* ws  = (float*)d_ws;

    void* args[] = {(void*)&wt, (void*)&mt, (void*)&lwt, (void*)&lmt,
                    (void*)&ws, (void*)&out};
    hipLaunchCooperativeKernel((const void*)rnc_all, dim3(GRID), dim3(NT),
                               args, 0, stream);
}

// Round 11
// 77.922 us; speedup vs baseline: 2.1107x; 2.1107x over previous
//
#include <hip/hip_runtime.h>

#define N 512          // n = 2*B
#define B 256
#define D 512
#define NT 512         // block size for sort/main
#define NBLK (N / 2)   // 256 main blocks, 2 rows each

// ws layout (float offsets)
#define WS_SL    0                    // [N] sorted labels ascending
#define WS_NORM  512                  // [N] ||f16||^2 (fp32) by sorted position
#define WS_SUM   1024                 // [1] float loss accumulator
#define WS_CNT   1025                 // [1] uint ticket
#define WS_FH    2048                 // N*D _Float16 sorted features (512 KB)
#define WS_G     (2048 + (N * D) / 2) // [N*N] fp32 Gram matrix (1 MB)

typedef _Float16 half4_t  __attribute__((ext_vector_type(4)));
typedef _Float16 half8_t  __attribute__((ext_vector_type(8)));
typedef float    f32x4    __attribute__((ext_vector_type(4)));

// ---- kernel 1 (grid 16): ranks + permute rows to sorted order as fp16 ----
__global__ __launch_bounds__(NT) void sort_rows_kernel(
    const float* __restrict__ wt, const float* __restrict__ mt,
    const float* __restrict__ lwt, const float* __restrict__ lmt,
    float* __restrict__ ws)
{
    const int t = threadIdx.x, b = blockIdx.x;
    __shared__ float slab[N];
    __shared__ int scnt[32];
    slab[t] = (t < B) ? lwt[t] : lmt[t - B];
    if (t < 32) scnt[t] = 0;
    __syncthreads();

    // rank of j = b*32 + (t&31); chunk c = t>>5 covers x in [c*32, c*32+32)
    const int jj = t & 31, j = b * 32 + jj, c = t >> 5;
    const float lj = slab[j];
    int r = 0;
    #pragma unroll 8
    for (int x = c * 32; x < c * 32 + 32; ++x) {
        const float v = slab[x];
        r += (v < lj || (v == lj && x < j)) ? 1 : 0;
    }
    atomicAdd(&scnt[jj], r);
    __syncthreads();

    if (t < 32)
        ws[WS_SL + scnt[t]] = slab[b * 32 + t];
    if (b == 0 && t == 0) {
        ws[WS_SUM] = 0.f;                     // stream-ordered before rnc_main
        ((unsigned*)ws)[WS_CNT] = 0u;
    }

    // permute rows [b*32, b*32+32) into sorted fp16; norms of rounded values
    const int row = b * 32 + (t >> 4), s16 = t & 15;
    const int rr = scnt[t >> 4];              // sorted position of row
    const float* F = (row < B) ? (wt + (size_t)row * D) : (mt + (size_t)(row - B) * D);
    const float4* F4 = (const float4*)F;
    half4_t* Dst = (half4_t*)((_Float16*)(ws + WS_FH) + (size_t)rr * D);
    float nacc = 0.f;
    #pragma unroll
    for (int q = 0; q < 8; ++q) {
        const int idx = s16 + 16 * q;
        const float4 v = F4[idx];
        half4_t h;
        h[0] = (_Float16)v.x; h[1] = (_Float16)v.y;
        h[2] = (_Float16)v.z; h[3] = (_Float16)v.w;
        const float f0 = (float)h[0], f1 = (float)h[1];
        const float f2 = (float)h[2], f3 = (float)h[3];
        nacc += f0 * f0 + f1 * f1 + f2 * f2 + f3 * f3;
        Dst[idx] = h;                         // 8B/lane, coalesced per 16-lane group
    }
    nacc += __shfl_down(nacc, 8, 16);
    nacc += __shfl_down(nacc, 4, 16);
    nacc += __shfl_down(nacc, 2, 16);
    nacc += __shfl_down(nacc, 1, 16);
    if (s16 == 0) ws[WS_NORM + rr] = nacc;
}

// ---- kernel 2 (grid 256 x 256thr): MFMA Gram G = F16 * F16^T, fp32 out ----
__global__ __launch_bounds__(256) void gram_kernel(float* __restrict__ ws)
{
    const int lane = threadIdx.x & 63;
    const int wid  = blockIdx.x * 4 + (threadIdx.x >> 6);   // 0..1023
    const int ti = wid >> 5, tj = wid & 31;                 // 16x16 tile coords
    const int quad = lane >> 4, m = lane & 15;

    const _Float16* Fh = (const _Float16*)(ws + WS_FH);
    const _Float16* Arow = Fh + (size_t)(ti * 16 + m) * D + quad * 8;
    const _Float16* Brow = Fh + (size_t)(tj * 16 + m) * D + quad * 8;

    f32x4 acc = {0.f, 0.f, 0.f, 0.f};
    #pragma unroll
    for (int k0 = 0; k0 < D; k0 += 32) {
        const half8_t a = *(const half8_t*)(Arow + k0);
        const half8_t b = *(const half8_t*)(Brow + k0);
        acc = __builtin_amdgcn_mfma_f32_16x16x32_f16(a, b, acc, 0, 0, 0);
    }
    // C/D layout: col = lane&15, row = quad*4 + reg (Gram symmetric anyway)
    float* G = ws + WS_G;
    const int col = tj * 16 + m;
    #pragma unroll
    for (int rg = 0; rg < 4; ++rg)
        G[(size_t)(ti * 16 + quad * 4 + rg) * N + col] = acc[rg];
}

// ---- kernel 3 (grid 256): 2 rows/block; e from G, scan, binsearch,
//      ticket-based finalize (replaces the grid-1 finalize launch) ----
__global__ __launch_bounds__(NT) void rnc_main(
    float* __restrict__ ws, float* __restrict__ out)
{
    const int b = blockIdx.x, i0 = 2 * b, i1 = 2 * b + 1;  // sorted positions
    const int t = threadIdx.x;
    const int w = t >> 6, lane = t & 63;

    __shared__ float sl[N];
    __shared__ float snm[N];
    __shared__ __align__(16) float sp0[N];
    __shared__ __align__(16) float sf0[N];
    __shared__ __align__(16) float sp1[N];
    __shared__ __align__(16) float sf1[N];
    __shared__ float sred[NT / 64];

    sl[t]  = ws[WS_SL + t];
    snm[t] = ws[WS_NORM + t];
    __syncthreads();
    const float li0 = sl[i0], li1 = sl[i1];
    const float ni0 = snm[i0], ni1 = snm[i1];

    // ---- phase 1: e from precomputed Gram rows (coalesced 4 KB total) ----
    const float* G = ws + WS_G;
    const float g0 = G[(size_t)i0 * N + t];
    const float g1 = G[(size_t)i1 * N + t];
    const float d0 = fmaxf(ni0 + snm[t] - 2.f * g0, 0.f);
    const float d1 = fmaxf(ni1 + snm[t] - 2.f * g1, 0.f);
    const float lg0 = -0.5f * sqrtf(d0);
    const float lg1 = -0.5f * sqrtf(d1);
    float lg_acc = 0.f;
    if (t != i0) lg_acc += lg0;
    if (t != i1) lg_acc += lg1;
    const float e0 = (t == i0) ? 0.f : __expf(lg0);
    const float e1 = (t == i1) ? 0.f : __expf(lg1);
    sp0[t] = e0; sf0[t] = e0;
    sp1[t] = e1; sf1[t] = e1;
    __syncthreads();

    // ---- phase 2a: wave-parallel scans (no block barriers inside) ----
    if (w < 4) {
        float* arr = (w == 0) ? sp0 : (w == 1) ? sf0 : (w == 2) ? sp1 : sf1;
        float4* a4 = (float4*)arr;
        float4 u0 = a4[lane * 2], u1 = a4[lane * 2 + 1];
        float v0 = u0.x, v1 = u0.y, v2 = u0.z, v3 = u0.w;
        float v4 = u1.x, v5 = u1.y, v6 = u1.z, v7 = u1.w;
        if ((w & 1) == 0) {                    // inclusive prefix scan
            v1 += v0; v2 += v1; v3 += v2; v4 += v3; v5 += v4; v6 += v5; v7 += v6;
            float x = v7;
            #pragma unroll
            for (int off = 1; off < 64; off <<= 1) {
                const float y = __shfl_up(x, off, 64);
                if (lane >= off) x += y;
            }
            float ex = __shfl_up(x, 1, 64);
            if (lane == 0) ex = 0.f;
            v0 += ex; v1 += ex; v2 += ex; v3 += ex; v4 += ex; v5 += ex; v6 += ex; v7 += ex;
        } else {                               // inclusive suffix scan
            v6 += v7; v5 += v6; v4 += v5; v3 += v4; v2 += v3; v1 += v2; v0 += v1;
            float x = v0;
            #pragma unroll
            for (int off = 1; off < 64; off <<= 1) {
                const float y = __shfl_down(x, off, 64);
                if (lane + off < 64) x += y;
            }
            float ex = __shfl_down(x, 1, 64);
            if (lane == 63) ex = 0.f;
            v0 += ex; v1 += ex; v2 += ex; v3 += ex; v4 += ex; v5 += ex; v6 += ex; v7 += ex;
        }
        a4[lane * 2]     = make_float4(v0, v1, v2, v3);
        a4[lane * 2 + 1] = make_float4(v4, v5, v6, v7);
    }
    __syncthreads();

    // ---- phase 2b: per-k denom via two exact binary searches (ri == i) ----
    float local = lg_acc;
    #pragma unroll
    for (int p = 0; p < 2; ++p) {
        const int x = t;                      // sorted position of k
        const int ri = p ? i1 : i0;
        const float li = p ? li1 : li0;
        const float* SP = p ? sp1 : sp0;
        const float* SF = p ? sf1 : sf0;
        if (x != ri) {
            const float th = fabsf(li - sl[x]);
            int lo = 0, hi = ri + 1;          // left branch: weakly decreasing
            while (lo < hi) {
                const int mid = (lo + hi) >> 1;
                if (fabsf(li - sl[mid]) >= th) lo = mid + 1; else hi = mid;
            }
            const int a = lo;
            lo = ri + 1; hi = N;              // right branch: weakly increasing
            while (lo < hi) {
                const int mid = (lo + hi) >> 1;
                if (fabsf(li - sl[mid]) >= th) hi = mid; else lo = mid + 1;
            }
            const int bb = lo;
            const float denom = ((a > 0) ? SP[a - 1] : 0.f) + ((bb < N) ? SF[bb] : 0.f);
            local -= __logf(denom);
        }
    }

    // ---- block reduction + ticket finalize ----
    #pragma unroll
    for (int off = 32; off > 0; off >>= 1)
        local += __shfl_down(local, off, 64);
    if (lane == 0) sred[w] = local;
    __syncthreads();
    if (t == 0) {
        float sum = 0.f;
        #pragma unroll
        for (int k = 0; k < NT / 64; ++k) sum += sred[k];
        atomicAdd(&ws[WS_SUM], sum);
        __threadfence();                      // release our add
        const unsigned old = atomicAdd(&((unsigned*)ws)[WS_CNT], 1u);
        if (old == NBLK - 1) {                // last block sees all adds
            __threadfence();
            const float total = atomicAdd(&ws[WS_SUM], 0.f);  // coherent read
            out[0] = -total / (float)((long)N * (N - 1));
        }
    }
}

extern "C" void kernel_launch(void* const* d_in, const int* in_sizes, int n_in,
                              void* d_out, int out_size, void* d_ws, size_t ws_size,
                              hipStream_t stream) {
    const float* wt  = (const float*)d_in[0];
    const float* mt  = (const float*)d_in[1];
    const float* lwt = (const float*)d_in[2];
    const float* lmt = (const float*)d_in[3];
    float* out = (float*)d_out;
    float* ws  = (float*)d_ws;

    sort_rows_kernel<<<16, NT, 0, stream>>>(wt, mt, lwt, lmt, ws);
    gram_kernel<<<256, 256, 0, stream>>>(ws);
    rnc_main<<<NBLK, NT, 0, stream>>>(ws, out);
}

// Round 12
// 74.613 us; speedup vs baseline: 2.2043x; 1.0444x over previous
//
#include <hip/hip_runtime.h>

// R8 structure — measured optimum (74.8 us). 4 dispatches, no device fences:
//   sort_rows (16 blk)  : label ranks + permute rows to sorted fp16 + norms
//   gram      (256 blk) : MFMA f16 Gram, fp32 out (G symmetric -> layout-safe)
//   main      (256 blk) : e from G rows, wave scans, exact binsearch denom
//   finalize  (1 blk)   : reduce 256 partials
// Measured regressions to avoid: ticket+threadfence finalize (+3us, R11),
// 2-kernel merge with orig-order Gram (+5.5us, R9), cooperative grid.sync
// (+90us, R10), fp16 phase-1 in main (+4us, R6), in-loop norms (+11us, R5).

#define N 512          // n = 2*B
#define B 256
#define D 512
#define NT 512         // block size for sort/main
#define NBLK (N / 2)   // 256 main blocks, 2 rows each

// ws layout (float offsets)
#define WS_SL    0                    // [N] sorted labels ascending
#define WS_NORM  512                  // [N] ||f16||^2 (fp32) by sorted position
#define WS_PART  1024                 // [NBLK] per-block partial sums
#define WS_FH    2048                 // N*D _Float16 sorted features (512 KB)
#define WS_G     (2048 + (N * D) / 2) // [N*N] fp32 Gram matrix (1 MB)

typedef _Float16 half4_t  __attribute__((ext_vector_type(4)));
typedef _Float16 half8_t  __attribute__((ext_vector_type(8)));
typedef float    f32x4    __attribute__((ext_vector_type(4)));

// ---- kernel 1 (grid 16): ranks + permute rows to sorted order as fp16 ----
__global__ __launch_bounds__(NT) void sort_rows_kernel(
    const float* __restrict__ wt, const float* __restrict__ mt,
    const float* __restrict__ lwt, const float* __restrict__ lmt,
    float* __restrict__ ws)
{
    const int t = threadIdx.x, b = blockIdx.x;
    __shared__ float slab[N];
    __shared__ int scnt[32];
    slab[t] = (t < B) ? lwt[t] : lmt[t - B];
    if (t < 32) scnt[t] = 0;
    __syncthreads();

    // rank of j = b*32 + (t&31); chunk c = t>>5 covers x in [c*32, c*32+32)
    const int jj = t & 31, j = b * 32 + jj, c = t >> 5;
    const float lj = slab[j];
    int r = 0;
    #pragma unroll 8
    for (int x = c * 32; x < c * 32 + 32; ++x) {
        const float v = slab[x];
        r += (v < lj || (v == lj && x < j)) ? 1 : 0;
    }
    atomicAdd(&scnt[jj], r);
    __syncthreads();

    if (t < 32)
        ws[WS_SL + scnt[t]] = slab[b * 32 + t];

    // permute rows [b*32, b*32+32) into sorted fp16; norms of rounded values
    const int row = b * 32 + (t >> 4), s16 = t & 15;
    const int rr = scnt[t >> 4];              // sorted position of row
    const float* F = (row < B) ? (wt + (size_t)row * D) : (mt + (size_t)(row - B) * D);
    const float4* F4 = (const float4*)F;
    half4_t* Dst = (half4_t*)((_Float16*)(ws + WS_FH) + (size_t)rr * D);
    float nacc = 0.f;
    #pragma unroll
    for (int q = 0; q < 8; ++q) {
        const int idx = s16 + 16 * q;
        const float4 v = F4[idx];
        half4_t h;
        h[0] = (_Float16)v.x; h[1] = (_Float16)v.y;
        h[2] = (_Float16)v.z; h[3] = (_Float16)v.w;
        const float f0 = (float)h[0], f1 = (float)h[1];
        const float f2 = (float)h[2], f3 = (float)h[3];
        nacc += f0 * f0 + f1 * f1 + f2 * f2 + f3 * f3;
        Dst[idx] = h;                         // 8B/lane, coalesced per 16-lane group
    }
    nacc += __shfl_down(nacc, 8, 16);
    nacc += __shfl_down(nacc, 4, 16);
    nacc += __shfl_down(nacc, 2, 16);
    nacc += __shfl_down(nacc, 1, 16);
    if (s16 == 0) ws[WS_NORM + rr] = nacc;
}

// ---- kernel 2 (grid 256 x 256thr): MFMA Gram G = F16 * F16^T, fp32 out ----
__global__ __launch_bounds__(256) void gram_kernel(float* __restrict__ ws)
{
    const int lane = threadIdx.x & 63;
    const int wid  = blockIdx.x * 4 + (threadIdx.x >> 6);   // 0..1023
    const int ti = wid >> 5, tj = wid & 31;                 // 16x16 tile coords
    const int quad = lane >> 4, m = lane & 15;

    const _Float16* Fh = (const _Float16*)(ws + WS_FH);
    const _Float16* Arow = Fh + (size_t)(ti * 16 + m) * D + quad * 8;
    const _Float16* Brow = Fh + (size_t)(tj * 16 + m) * D + quad * 8;

    f32x4 acc = {0.f, 0.f, 0.f, 0.f};
    #pragma unroll
    for (int k0 = 0; k0 < D; k0 += 32) {
        const half8_t a = *(const half8_t*)(Arow + k0);   // A[m][quad*8+j]
        const half8_t b = *(const half8_t*)(Brow + k0);   // B[k=quad*8+j][n=m]
        acc = __builtin_amdgcn_mfma_f32_16x16x32_f16(a, b, acc, 0, 0, 0);
    }
    // C/D layout: col = lane&15, row = quad*4 + reg   (Gram symmetric ->
    // a row/col transposition here would be value-identical anyway)
    float* G = ws + WS_G;
    const int col = tj * 16 + m;
    #pragma unroll
    for (int rg = 0; rg < 4; ++rg)
        G[(size_t)(ti * 16 + quad * 4 + rg) * N + col] = acc[rg];
}

// ---- kernel 3 (grid 256): 2 rows/block; e from G, scan, binsearch ----
__global__ __launch_bounds__(NT) void rnc_main(float* __restrict__ ws)
{
    const int b = blockIdx.x, i0 = 2 * b, i1 = 2 * b + 1;  // sorted positions
    const int t = threadIdx.x;
    const int w = t >> 6, lane = t & 63;

    __shared__ float sl[N];
    __shared__ float snm[N];
    __shared__ __align__(16) float sp0[N];
    __shared__ __align__(16) float sf0[N];
    __shared__ __align__(16) float sp1[N];
    __shared__ __align__(16) float sf1[N];
    __shared__ float sred[NT / 64];

    sl[t]  = ws[WS_SL + t];
    snm[t] = ws[WS_NORM + t];
    __syncthreads();
    const float li0 = sl[i0], li1 = sl[i1];
    const float ni0 = snm[i0], ni1 = snm[i1];

    // ---- phase 1: e from precomputed Gram rows (coalesced 4 KB total) ----
    const float* G = ws + WS_G;
    const float g0 = G[(size_t)i0 * N + t];
    const float g1 = G[(size_t)i1 * N + t];
    const float d0 = fmaxf(ni0 + snm[t] - 2.f * g0, 0.f);
    const float d1 = fmaxf(ni1 + snm[t] - 2.f * g1, 0.f);
    const float lg0 = -0.5f * sqrtf(d0);
    const float lg1 = -0.5f * sqrtf(d1);
    float lg_acc = 0.f;
    if (t != i0) lg_acc += lg0;
    if (t != i1) lg_acc += lg1;
    const float e0 = (t == i0) ? 0.f : __expf(lg0);
    const float e1 = (t == i1) ? 0.f : __expf(lg1);
    sp0[t] = e0; sf0[t] = e0;
    sp1[t] = e1; sf1[t] = e1;
    __syncthreads();

    // ---- phase 2a: wave-parallel scans (no block barriers inside) ----
    if (w < 4) {
        float* arr = (w == 0) ? sp0 : (w == 1) ? sf0 : (w == 2) ? sp1 : sf1;
        float4* a4 = (float4*)arr;
        float4 u0 = a4[lane * 2], u1 = a4[lane * 2 + 1];
        float v0 = u0.x, v1 = u0.y, v2 = u0.z, v3 = u0.w;
        float v4 = u1.x, v5 = u1.y, v6 = u1.z, v7 = u1.w;
        if ((w & 1) == 0) {                    // inclusive prefix scan
            v1 += v0; v2 += v1; v3 += v2; v4 += v3; v5 += v4; v6 += v5; v7 += v6;
            float x = v7;
            #pragma unroll
            for (int off = 1; off < 64; off <<= 1) {
                const float y = __shfl_up(x, off, 64);
                if (lane >= off) x += y;
            }
            float ex = __shfl_up(x, 1, 64);
            if (lane == 0) ex = 0.f;
            v0 += ex; v1 += ex; v2 += ex; v3 += ex; v4 += ex; v5 += ex; v6 += ex; v7 += ex;
        } else {                               // inclusive suffix scan
            v6 += v7; v5 += v6; v4 += v5; v3 += v4; v2 += v3; v1 += v2; v0 += v1;
            float x = v0;
            #pragma unroll
            for (int off = 1; off < 64; off <<= 1) {
                const float y = __shfl_down(x, off, 64);
                if (lane + off < 64) x += y;
            }
            float ex = __shfl_down(x, 1, 64);
            if (lane == 63) ex = 0.f;
            v0 += ex; v1 += ex; v2 += ex; v3 += ex; v4 += ex; v5 += ex; v6 += ex; v7 += ex;
        }
        a4[lane * 2]     = make_float4(v0, v1, v2, v3);
        a4[lane * 2 + 1] = make_float4(v4, v5, v6, v7);
    }
    __syncthreads();

    // ---- phase 2b: per-k denom via two exact binary searches (ri == i) ----
    float local = lg_acc;
    #pragma unroll
    for (int p = 0; p < 2; ++p) {
        const int x = t;                      // sorted position of k
        const int ri = p ? i1 : i0;
        const float li = p ? li1 : li0;
        const float* SP = p ? sp1 : sp0;
        const float* SF = p ? sf1 : sf0;
        if (x != ri) {
            const float th = fabsf(li - sl[x]);
            int lo = 0, hi = ri + 1;          // left branch: weakly decreasing
            while (lo < hi) {
                const int mid = (lo + hi) >> 1;
                if (fabsf(li - sl[mid]) >= th) lo = mid + 1; else hi = mid;
            }
            const int a = lo;
            lo = ri + 1; hi = N;              // right branch: weakly increasing
            while (lo < hi) {
                const int mid = (lo + hi) >> 1;
                if (fabsf(li - sl[mid]) >= th) hi = mid; else lo = mid + 1;
            }
            const int bb = lo;
            const float denom = ((a > 0) ? SP[a - 1] : 0.f) + ((bb < N) ? SF[bb] : 0.f);
            local -= __logf(denom);
        }
    }

    // ---- block reduction, plain store ----
    #pragma unroll
    for (int off = 32; off > 0; off >>= 1)
        local += __shfl_down(local, off, 64);
    if (lane == 0) sred[w] = local;
    __syncthreads();
    if (t == 0) {
        float sum = 0.f;
        #pragma unroll
        for (int k = 0; k < NT / 64; ++k) sum += sred[k];
        ws[WS_PART + b] = sum;
    }
}

// ---- kernel 4: reduce 256 partials + finalize ----
__global__ __launch_bounds__(NBLK) void rnc_finalize(
    const float* __restrict__ ws, float* __restrict__ out)
{
    const int t = threadIdx.x;
    __shared__ float sred[NBLK / 64];
    float v = ws[WS_PART + t];
    #pragma unroll
    for (int off = 32; off > 0; off >>= 1)
        v += __shfl_down(v, off, 64);
    if ((t & 63) == 0) sred[t >> 6] = v;
    __syncthreads();
    if (t == 0) {
        float sum = 0.f;
        #pragma unroll
        for (int k = 0; k < NBLK / 64; ++k) sum += sred[k];
        out[0] = -sum / (float)((long)N * (N - 1));
    }
}

extern "C" void kernel_launch(void* const* d_in, const int* in_sizes, int n_in,
                              void* d_out, int out_size, void* d_ws, size_t ws_size,
                              hipStream_t stream) {
    const float* wt  = (const float*)d_in[0];
    const float* mt  = (const float*)d_in[1];
    const float* lwt = (const float*)d_in[2];
    const float* lmt = (const float*)d_in[3];
    float* out = (float*)d_out;
    float* ws  = (float*)d_ws;

    sort_rows_kernel<<<16, NT, 0, stream>>>(wt, mt, lwt, lmt, ws);
    gram_kernel<<<256, 256, 0, stream>>>(ws);
    rnc_main<<<NBLK, NT, 0, stream>>>(ws);
    rnc_finalize<<<1, NBLK, 0, stream>>>(ws, out);
}